// Round 7
// baseline (186.771 us; speedup 1.0000x reference)
//
#include <hip/hip_runtime.h>
#include <hip/hip_bf16.h>
#include <math.h>

#define ZD 64      // output channels
#define IC 256     // input channels
#define BSH 7      // bucket shift: bucket = dst >> 7 (128 nodes/bucket)
#define BCAP 2560  // recs per bucket region (mean 2048, sigma~45 -> +11 sigma)
#define EPW 2048   // edges per binning workgroup

using bf16x8 = __attribute__((ext_vector_type(8))) short;
using f32x4  = __attribute__((ext_vector_type(4))) float;

__device__ __forceinline__ short f2bf(float f) {
    __hip_bfloat16 h = __float2bfloat16(f);   // RNE
    return *reinterpret_cast<short*>(&h);
}
__device__ __forceinline__ float bf2f(unsigned short u) {
    unsigned v = ((unsigned)u) << 16;
    return __builtin_bit_cast(float, v);
}

// ---------------- init bucket cursors to region bases ---------------------
__global__ __launch_bounds__(512) void k_init(unsigned* __restrict__ bcur, int NBK) {
    int t = threadIdx.x;
    if (t < NBK) bcur[t] = (unsigned)t * BCAP;
}

// ---------------- bin edges into per-bucket regions -----------------------
// rec = (dst<<16)|src (both < 65536). Per-WG LDS histogram -> one global
// atomic per (WG,bucket) -> scatter (short contiguous runs per bucket).
__global__ __launch_bounds__(256) void k_bin(const int* __restrict__ src,
                                             const int* __restrict__ dst, int E,
                                             unsigned* __restrict__ bcur,
                                             unsigned* __restrict__ binned, int NBK) {
    __shared__ unsigned hist[512], lbase[512], lcur[512];
    int t = threadIdx.x;
    for (int i = t; i < NBK; i += 256) { hist[i] = 0u; lcur[i] = 0u; }
    __syncthreads();
    int base = blockIdx.x * EPW;
#pragma unroll
    for (int i = 0; i < EPW / 256; ++i) {
        int e = base + i * 256 + t;
        if (e < E) atomicAdd(&hist[((unsigned)dst[e]) >> BSH], 1u);
    }
    __syncthreads();
    for (int i = t; i < NBK; i += 256) {
        unsigned c = hist[i];
        lbase[i] = c ? atomicAdd(&bcur[i], c) : 0u;
    }
    __syncthreads();
#pragma unroll
    for (int i = 0; i < EPW / 256; ++i) {
        int e = base + i * 256 + t;
        if (e < E) {
            unsigned d = (unsigned)dst[e];
            unsigned bk = d >> BSH;
            unsigned pos = lbase[bk] + atomicAdd(&lcur[bk], 1u);
            binned[pos] = (d << 16) | (unsigned)src[e];
        }
    }
}

// ---------------- per-bucket degree -> dinv (contiguous writes) -----------
__global__ __launch_bounds__(256) void k_deg2(const unsigned* __restrict__ bcur,
                                              const unsigned* __restrict__ binned,
                                              float* __restrict__ dinv, int N) {
    int b = blockIdx.x, t = threadIdx.x;
    __shared__ unsigned hist[128];
    if (t < 128) hist[t] = 0u;
    __syncthreads();
    unsigned cnt = bcur[b] - (unsigned)b * BCAP;
    const unsigned* recs = binned + (size_t)b * BCAP;
    for (unsigned i = t; i < cnt; i += 256)
        atomicAdd(&hist[(recs[i] >> 16) & 127u], 1u);
    __syncthreads();
    if (t < 128) {
        int node = b * 128 + t;
        if (node < N) dinv[node] = rsqrtf((float)hist[t] + 1.0f);  // +1 self-loop
    }
}

// ---------------- pack W into per-lane B-fragment order -------------------
__global__ __launch_bounds__(256) void k_packw(const float* __restrict__ W,
                                               unsigned short* __restrict__ Bpack) {
    int e = blockIdx.x * 256 + threadIdx.x;   // 0..16383
    int j = e & 7;
    int lane = (e >> 3) & 63;
    int ct = (e >> 9) & 3;
    int s = e >> 11;
    int c = ct * 16 + (lane & 15);
    int k = s * 32 + (lane >> 4) * 8 + j;
    Bpack[e] = (unsigned short)f2bf(W[c * IC + k]);
}

// ---------------- MFMA linear + L2-normalize*1.8, scaled by dinv ----------
// Grid-stride over 64-row tiles; Bpack staged to LDS once per block.
// g stored as bf16 (halves the gather kernel's traffic).
__global__ __launch_bounds__(256) void k_linnorm_mfma(
    const float* __restrict__ x, const unsigned short* __restrict__ Bpack,
    const float* __restrict__ b, const float* __restrict__ dinv,
    unsigned short* __restrict__ g, int N) {
    __shared__ uint4 bp[2048];  // 32 KB

    const uint4* bg = (const uint4*)Bpack;
#pragma unroll
    for (int i = 0; i < 8; ++i) bp[i * 256 + threadIdx.x] = bg[i * 256 + threadIdx.x];
    __syncthreads();

    int lane = threadIdx.x & 63;
    int w = threadIdx.x >> 6;
    int r = lane & 15;        // A-row / D-col index
    int grp = lane >> 4;      // k-group / D-row group
    const bf16x8* bpv = (const bf16x8*)bp;

    int T = (N + 63) >> 6;    // 64-row tiles
    for (int tile = blockIdx.x; tile < T; tile += gridDim.x) {
        int row0 = tile * 64 + w * 16;
        if (row0 >= N) continue;

        int rowA = row0 + r; if (rowA >= N) rowA = N - 1;
        const float* xr = x + (size_t)rowA * IC;

        f32x4 acc[4];
#pragma unroll
        for (int ct = 0; ct < 4; ++ct) {
            float bb = b[ct * 16 + r];
            acc[ct] = (f32x4){bb, bb, bb, bb};
        }

#pragma unroll
        for (int s = 0; s < 8; ++s) {
            const float4* pa = (const float4*)(xr + s * 32 + grp * 8);
            float4 v0 = pa[0], v1 = pa[1];
            bf16x8 a;
            a[0] = f2bf(v0.x); a[1] = f2bf(v0.y); a[2] = f2bf(v0.z); a[3] = f2bf(v0.w);
            a[4] = f2bf(v1.x); a[5] = f2bf(v1.y); a[6] = f2bf(v1.z); a[7] = f2bf(v1.w);
#pragma unroll
            for (int ct = 0; ct < 4; ++ct) {
                bf16x8 bfr = bpv[(s * 4 + ct) * 64 + lane];
                acc[ct] = __builtin_amdgcn_mfma_f32_16x16x32_bf16(a, bfr, acc[ct], 0, 0, 0);
            }
        }

        // per-row: row = row0 + grp*4 + reg, col = ct*16 + r
#pragma unroll
        for (int reg = 0; reg < 4; ++reg) {
            float ss = 0.f;
#pragma unroll
            for (int ct = 0; ct < 4; ++ct) ss += acc[ct][reg] * acc[ct][reg];
#pragma unroll
            for (int o = 1; o < 16; o <<= 1) ss += __shfl_xor(ss, o, 16);

            int rowg = row0 + grp * 4 + reg;
            int rc = rowg < N ? rowg : N - 1;
            float sc = 1.8f / fmaxf(sqrtf(ss), 1e-12f) * dinv[rc];
            if (rowg < N) {
                unsigned short* go = g + (size_t)rowg * ZD + r;
#pragma unroll
                for (int ct = 0; ct < 4; ++ct)
                    go[ct * 16] = (unsigned short)f2bf(acc[ct][reg] * sc);
            }
        }
    }
}

// ---------------- per-half-bucket local CSR + gather (bf16 g) -------------
// WG = (bucket b, half hf): 64 dst nodes. Local CSR lives entirely in LDS.
__global__ __launch_bounds__(256) void k_gather2(
    const unsigned* __restrict__ bcur, const unsigned* __restrict__ binned,
    const float* __restrict__ dinv, const unsigned short* __restrict__ g,
    float* __restrict__ out, int N) {
    int wg = blockIdx.x, b = wg >> 1, hf = wg & 1;
    __shared__ unsigned hist[64], rp[65], lcu[64];
    __shared__ unsigned short lcsr[2048];
    int t = threadIdx.x, lane = t & 63, w = t >> 6;
    if (t < 64) hist[t] = 0u;
    __syncthreads();

    unsigned cnt = bcur[b] - (unsigned)b * BCAP;
    const unsigned* recs = binned + (size_t)b * BCAP;

    for (unsigned i = t; i < cnt; i += 256) {
        unsigned dl = (recs[i] >> 16) & 127u;
        if ((int)(dl >> 6) == hf) atomicAdd(&hist[dl & 63u], 1u);
    }
    __syncthreads();
    if (w == 0) {  // wave 0: 64-lane inclusive scan of counts
        unsigned v = hist[lane], incl = v;
#pragma unroll
        for (int d = 1; d < 64; d <<= 1) {
            unsigned u = __shfl_up(incl, d, 64);
            if (lane >= d) incl += u;
        }
        rp[lane + 1] = incl;
        if (lane == 0) rp[0] = 0u;
        lcu[lane] = incl - v;  // exclusive base as running cursor
    }
    __syncthreads();
    for (unsigned i = t; i < cnt; i += 256) {
        unsigned rec = recs[i];
        unsigned dl = (rec >> 16) & 127u;
        if ((int)(dl >> 6) == hf) {
            unsigned p = atomicAdd(&lcu[dl & 63u], 1u);
            lcsr[p] = (unsigned short)(rec & 0xFFFFu);
        }
    }
    __syncthreads();

    // wave w gathers nodes w*16 .. w*16+15 of this half
    for (int q = 0; q < 16; ++q) {
        int nl = w * 16 + q;
        int node = b * 128 + hf * 64 + nl;
        if (node >= N) break;  // uniform per wave
        unsigned j = rp[nl], je = rp[nl + 1];
        float acc = bf2f(g[(size_t)node * ZD + lane]);  // self-loop term
        for (; j + 8 <= je; j += 8) {
            unsigned short s0 = lcsr[j],     s1 = lcsr[j + 1];
            unsigned short s2 = lcsr[j + 2], s3 = lcsr[j + 3];
            unsigned short s4 = lcsr[j + 4], s5 = lcsr[j + 5];
            unsigned short s6 = lcsr[j + 6], s7 = lcsr[j + 7];
            float v0 = bf2f(g[(size_t)s0 * ZD + lane]);
            float v1 = bf2f(g[(size_t)s1 * ZD + lane]);
            float v2 = bf2f(g[(size_t)s2 * ZD + lane]);
            float v3 = bf2f(g[(size_t)s3 * ZD + lane]);
            float v4 = bf2f(g[(size_t)s4 * ZD + lane]);
            float v5 = bf2f(g[(size_t)s5 * ZD + lane]);
            float v6 = bf2f(g[(size_t)s6 * ZD + lane]);
            float v7 = bf2f(g[(size_t)s7 * ZD + lane]);
            acc += ((v0 + v1) + (v2 + v3)) + ((v4 + v5) + (v6 + v7));
        }
        for (; j < je; ++j) acc += bf2f(g[(size_t)lcsr[j] * ZD + lane]);
        out[(size_t)node * ZD + lane] = dinv[node] * acc;
    }
}

extern "C" void kernel_launch(void* const* d_in, const int* in_sizes, int n_in,
                              void* d_out, int out_size, void* d_ws, size_t ws_size,
                              hipStream_t stream) {
    const float* x = (const float*)d_in[0];
    const float* W = (const float*)d_in[1];
    const float* b = (const float*)d_in[2];
    const int* edge_index = (const int*)d_in[3];

    const int N = in_sizes[0] / IC;   // 50000
    const int E = in_sizes[3] / 2;    // 800000
    const int* src = edge_index;
    const int* dst = edge_index + E;
    float* out = (float*)d_out;

    const int NBK = (N + 127) >> BSH;   // 391 buckets

    // ---- workspace carve-up (256B aligned) ----
    char* p = (char*)d_ws;
    auto carve = [&](size_t bytes) {
        char* r = p;
        p += (bytes + 255) & ~(size_t)255;
        return r;
    };
    unsigned short* g      = (unsigned short*)carve((size_t)N * ZD * sizeof(unsigned short));
    float*          dinv   = (float*)         carve((size_t)N * sizeof(float));
    unsigned*       bcur   = (unsigned*)      carve(512 * sizeof(unsigned));
    unsigned short* Bpack  = (unsigned short*)carve(16384 * sizeof(unsigned short));
    unsigned*       binned = (unsigned*)      carve((size_t)NBK * BCAP * sizeof(unsigned));

    k_init<<<1, 512, 0, stream>>>(bcur, NBK);
    k_packw<<<64, 256, 0, stream>>>(W, Bpack);
    k_bin<<<(E + EPW - 1) / EPW, 256, 0, stream>>>(src, dst, E, bcur, binned, NBK);
    k_deg2<<<NBK, 256, 0, stream>>>(bcur, binned, dinv, N);
    k_linnorm_mfma<<<260, 256, 0, stream>>>(x, Bpack, b, dinv, g, N);
    k_gather2<<<2 * NBK, 256, 0, stream>>>(bcur, binned, dinv, g, out, N);
}

// Round 10
// 162.737 us; speedup vs baseline: 1.1477x; 1.1477x over previous
//
#include <hip/hip_runtime.h>
#include <hip/hip_bf16.h>
#include <math.h>

#define ZD 64      // output channels
#define IC 256     // input channels
#define BSH 7      // bucket shift: bucket = dst >> 7 (128 nodes/bucket)
#define BCAP 2560  // recs per bucket region (mean 2048, sigma~45 -> +11 sigma)
#define EPW 2048   // edges per binning workgroup

using bf16x8 = __attribute__((ext_vector_type(8))) short;
using f32x4  = __attribute__((ext_vector_type(4))) float;

__device__ __forceinline__ short f2bf(float f) {
    __hip_bfloat16 h = __float2bfloat16(f);   // RNE
    return *reinterpret_cast<short*>(&h);
}
__device__ __forceinline__ float bflo(unsigned u) {  // low ushort -> f32
    return __builtin_bit_cast(float, u << 16);
}
__device__ __forceinline__ float bfhi(unsigned u) {  // high ushort -> f32
    return __builtin_bit_cast(float, u & 0xFFFF0000u);
}

// ---------------- init bucket cursors to region bases ---------------------
__global__ __launch_bounds__(512) void k_init(unsigned* __restrict__ bcur, int NBK) {
    int t = threadIdx.x;
    if (t < NBK) bcur[t] = (unsigned)t * BCAP;
}

// ---------------- bin edges into per-bucket regions -----------------------
__global__ __launch_bounds__(256) void k_bin(const int* __restrict__ src,
                                             const int* __restrict__ dst, int E,
                                             unsigned* __restrict__ bcur,
                                             unsigned* __restrict__ binned, int NBK) {
    __shared__ unsigned hist[512], lbase[512], lcur[512];
    int t = threadIdx.x;
    for (int i = t; i < NBK; i += 256) { hist[i] = 0u; lcur[i] = 0u; }
    __syncthreads();
    int base = blockIdx.x * EPW;
#pragma unroll
    for (int i = 0; i < EPW / 256; ++i) {
        int e = base + i * 256 + t;
        if (e < E) atomicAdd(&hist[((unsigned)dst[e]) >> BSH], 1u);
    }
    __syncthreads();
    for (int i = t; i < NBK; i += 256) {
        unsigned c = hist[i];
        lbase[i] = c ? atomicAdd(&bcur[i], c) : 0u;
    }
    __syncthreads();
#pragma unroll
    for (int i = 0; i < EPW / 256; ++i) {
        int e = base + i * 256 + t;
        if (e < E) {
            unsigned d = (unsigned)dst[e];
            unsigned bk = d >> BSH;
            unsigned pos = lbase[bk] + atomicAdd(&lcur[bk], 1u);
            binned[pos] = (d << 16) | (unsigned)src[e];
        }
    }
}

// ---------------- per-bucket degree -> dinv (contiguous writes) -----------
__global__ __launch_bounds__(256) void k_deg2(const unsigned* __restrict__ bcur,
                                              const unsigned* __restrict__ binned,
                                              float* __restrict__ dinv, int N) {
    int b = blockIdx.x, t = threadIdx.x;
    __shared__ unsigned hist[128];
    if (t < 128) hist[t] = 0u;
    __syncthreads();
    unsigned cnt = bcur[b] - (unsigned)b * BCAP;
    const unsigned* recs = binned + (size_t)b * BCAP;
    for (unsigned i = t; i < cnt; i += 256)
        atomicAdd(&hist[(recs[i] >> 16) & 127u], 1u);
    __syncthreads();
    if (t < 128) {
        int node = b * 128 + t;
        if (node < N) dinv[node] = rsqrtf((float)hist[t] + 1.0f);  // +1 self-loop
    }
}

// ---------------- pack W into per-lane B-fragment order -------------------
__global__ __launch_bounds__(256) void k_packw(const float* __restrict__ W,
                                               unsigned short* __restrict__ Bpack) {
    int e = blockIdx.x * 256 + threadIdx.x;   // 0..16383
    int j = e & 7;
    int lane = (e >> 3) & 63;
    int ct = (e >> 9) & 3;
    int s = e >> 11;
    int c = ct * 16 + (lane & 15);
    int k = s * 32 + (lane >> 4) * 8 + j;
    Bpack[e] = (unsigned short)f2bf(W[c * IC + k]);
}

// ---------------- MFMA linear + L2-normalize*1.8, scaled by dinv ----------
// Per-tile launch (782 blocks = ~3/CU): Bpack staged to LDS per block.
__global__ __launch_bounds__(256) void k_linnorm_mfma(
    const float* __restrict__ x, const unsigned short* __restrict__ Bpack,
    const float* __restrict__ b, const float* __restrict__ dinv,
    unsigned short* __restrict__ g, int N) {
    __shared__ uint4 bp[2048];  // 32 KB

    const uint4* bg = (const uint4*)Bpack;
#pragma unroll
    for (int i = 0; i < 8; ++i) bp[i * 256 + threadIdx.x] = bg[i * 256 + threadIdx.x];
    __syncthreads();

    int lane = threadIdx.x & 63;
    int w = threadIdx.x >> 6;
    int row0 = blockIdx.x * 64 + w * 16;
    if (row0 >= N) return;

    int r = lane & 15;        // A-row / D-col index
    int grp = lane >> 4;      // k-group / D-row group

    int rowA = row0 + r; if (rowA >= N) rowA = N - 1;
    const float* xr = x + (size_t)rowA * IC;

    f32x4 acc[4];
#pragma unroll
    for (int ct = 0; ct < 4; ++ct) {
        float bb = b[ct * 16 + r];
        acc[ct] = (f32x4){bb, bb, bb, bb};
    }

    const bf16x8* bpv = (const bf16x8*)bp;
#pragma unroll
    for (int s = 0; s < 8; ++s) {
        const float4* pa = (const float4*)(xr + s * 32 + grp * 8);
        float4 v0 = pa[0], v1 = pa[1];
        bf16x8 a;
        a[0] = f2bf(v0.x); a[1] = f2bf(v0.y); a[2] = f2bf(v0.z); a[3] = f2bf(v0.w);
        a[4] = f2bf(v1.x); a[5] = f2bf(v1.y); a[6] = f2bf(v1.z); a[7] = f2bf(v1.w);
#pragma unroll
        for (int ct = 0; ct < 4; ++ct) {
            bf16x8 bfr = bpv[(s * 4 + ct) * 64 + lane];
            acc[ct] = __builtin_amdgcn_mfma_f32_16x16x32_bf16(a, bfr, acc[ct], 0, 0, 0);
        }
    }

    // per-row: row = row0 + grp*4 + reg, col = ct*16 + r
#pragma unroll
    for (int reg = 0; reg < 4; ++reg) {
        float ss = 0.f;
#pragma unroll
        for (int ct = 0; ct < 4; ++ct) ss += acc[ct][reg] * acc[ct][reg];
#pragma unroll
        for (int o = 1; o < 16; o <<= 1) ss += __shfl_xor(ss, o, 16);

        int rowg = row0 + grp * 4 + reg;
        int rc = rowg < N ? rowg : N - 1;
        float sc = 1.8f / fmaxf(sqrtf(ss), 1e-12f) * dinv[rc];
        if (rowg < N) {
            unsigned short* go = g + (size_t)rowg * ZD + r;
#pragma unroll
            for (int ct = 0; ct < 4; ++ct)
                go[ct * 16] = (unsigned short)f2bf(acc[ct][reg] * sc);
        }
    }
}

// ---------------- per-half-bucket local CSR + 4-edge-wide gather ----------
// WG = (bucket b, half hf): 64 dst nodes. 16-lane group = one edge;
// lane holds 4 channels (uint2 of bf16). Cross-group combine via 2 shfl_xor.
__global__ __launch_bounds__(256) void k_gather2(
    const unsigned* __restrict__ bcur, const unsigned* __restrict__ binned,
    const float* __restrict__ dinv, const unsigned short* __restrict__ g,
    float* __restrict__ out, int N) {
    int wg = blockIdx.x, b = wg >> 1, hf = wg & 1;
    __shared__ unsigned hist[64], rp[65], lcu[64];
    __shared__ unsigned short lcsr[2052];   // +4 pad: predicated reads at je..je+3
    int t = threadIdx.x, lane = t & 63, w = t >> 6;
    if (t < 64) hist[t] = 0u;
    __syncthreads();

    unsigned cnt = bcur[b] - (unsigned)b * BCAP;
    const unsigned* recs = binned + (size_t)b * BCAP;

    for (unsigned i = t; i < cnt; i += 256) {
        unsigned dl = (recs[i] >> 16) & 127u;
        if ((int)(dl >> 6) == hf) atomicAdd(&hist[dl & 63u], 1u);
    }
    __syncthreads();
    if (w == 0) {  // wave 0: 64-lane inclusive scan of counts
        unsigned v = hist[lane], incl = v;
#pragma unroll
        for (int d = 1; d < 64; d <<= 1) {
            unsigned u = __shfl_up(incl, d, 64);
            if (lane >= d) incl += u;
        }
        rp[lane + 1] = incl;
        if (lane == 0) rp[0] = 0u;
        lcu[lane] = incl - v;  // exclusive base as running cursor
    }
    __syncthreads();
    for (unsigned i = t; i < cnt; i += 256) {
        unsigned rec = recs[i];
        unsigned dl = (rec >> 16) & 127u;
        if ((int)(dl >> 6) == hf) {
            unsigned p = atomicAdd(&lcu[dl & 63u], 1u);
            lcsr[p] = (unsigned short)(rec & 0xFFFFu);
        }
    }
    __syncthreads();

    int sub = lane & 15;     // channel quad: ch = sub*4 .. sub*4+3
    int grp = lane >> 4;     // edge slot within the 4-wide group
    float gsel = (grp == 0) ? 1.f : 0.f;

    // wave w gathers nodes w*16 .. w*16+15 of this half
    for (int q = 0; q < 16; ++q) {
        int nl = w * 16 + q;
        int node = b * 128 + hf * 64 + nl;
        if (node >= N) break;  // uniform per wave
        unsigned j = rp[nl], je = rp[nl + 1];

        // self-loop term, group 0 only (groups are summed at the end)
        uint2 sv = *(const uint2*)(g + (size_t)node * ZD + sub * 4);
        float a0 = bflo(sv.x) * gsel, a1 = bfhi(sv.x) * gsel;
        float a2 = bflo(sv.y) * gsel, a3 = bfhi(sv.y) * gsel;

        for (; j + 8 <= je; j += 8) {            // 8 edges in flight per wave
            unsigned short s0 = lcsr[j + grp];
            unsigned short s1 = lcsr[j + 4 + grp];
            uint2 u0 = *(const uint2*)(g + (size_t)s0 * ZD + sub * 4);
            uint2 u1 = *(const uint2*)(g + (size_t)s1 * ZD + sub * 4);
            a0 += bflo(u0.x); a1 += bfhi(u0.x);
            a2 += bflo(u0.y); a3 += bfhi(u0.y);
            a0 += bflo(u1.x); a1 += bfhi(u1.x);
            a2 += bflo(u1.y); a3 += bfhi(u1.y);
        }
        for (; j < je; j += 4) {                 // predicated tail
            unsigned e = j + grp;
            unsigned short s0 = lcsr[e];         // padded array; value gated below
            uint2 u0 = *(const uint2*)(g + (size_t)s0 * ZD + sub * 4);
            float m = (e < je) ? 1.f : 0.f;
            a0 = fmaf(bflo(u0.x), m, a0); a1 = fmaf(bfhi(u0.x), m, a1);
            a2 = fmaf(bflo(u0.y), m, a2); a3 = fmaf(bfhi(u0.y), m, a3);
        }

        // sum the 4 edge-groups (each group holds all 64 channels)
#pragma unroll
        for (int o = 16; o < 64; o <<= 1) {
            a0 += __shfl_xor(a0, o, 64); a1 += __shfl_xor(a1, o, 64);
            a2 += __shfl_xor(a2, o, 64); a3 += __shfl_xor(a3, o, 64);
        }
        if (grp == 0) {
            float dv = dinv[node];
            float4 o4 = {a0 * dv, a1 * dv, a2 * dv, a3 * dv};
            *(float4*)(out + (size_t)node * ZD + sub * 4) = o4;
        }
    }
}

extern "C" void kernel_launch(void* const* d_in, const int* in_sizes, int n_in,
                              void* d_out, int out_size, void* d_ws, size_t ws_size,
                              hipStream_t stream) {
    const float* x = (const float*)d_in[0];
    const float* W = (const float*)d_in[1];
    const float* b = (const float*)d_in[2];
    const int* edge_index = (const int*)d_in[3];

    const int N = in_sizes[0] / IC;   // 50000
    const int E = in_sizes[3] / 2;    // 800000
    const int* src = edge_index;
    const int* dst = edge_index + E;
    float* out = (float*)d_out;

    const int NBK = (N + 127) >> BSH;   // 391 buckets

    // ---- workspace carve-up (256B aligned) ----
    char* p = (char*)d_ws;
    auto carve = [&](size_t bytes) {
        char* r = p;
        p += (bytes + 255) & ~(size_t)255;
        return r;
    };
    unsigned short* g      = (unsigned short*)carve((size_t)N * ZD * sizeof(unsigned short));
    float*          dinv   = (float*)         carve((size_t)N * sizeof(float));
    unsigned*       bcur   = (unsigned*)      carve(512 * sizeof(unsigned));
    unsigned short* Bpack  = (unsigned short*)carve(16384 * sizeof(unsigned short));
    unsigned*       binned = (unsigned*)      carve((size_t)NBK * BCAP * sizeof(unsigned));

    k_init<<<1, 512, 0, stream>>>(bcur, NBK);
    k_packw<<<64, 256, 0, stream>>>(W, Bpack);
    k_bin<<<(E + EPW - 1) / EPW, 256, 0, stream>>>(src, dst, E, bcur, binned, NBK);
    k_deg2<<<NBK, 256, 0, stream>>>(bcur, binned, dinv, N);
    k_linnorm_mfma<<<(N + 63) / 64, 256, 0, stream>>>(x, Bpack, b, dinv, g, N);
    k_gather2<<<2 * NBK, 256, 0, stream>>>(bcur, binned, dinv, g, out, N);
}

// Round 12
// 147.843 us; speedup vs baseline: 1.2633x; 1.1007x over previous
//
#include <hip/hip_runtime.h>
#include <hip/hip_bf16.h>
#include <math.h>

#define ZD 64      // output channels
#define IC 256     // input channels
#define BSH 7      // bucket shift: bucket = dst >> 7 (128 nodes/bucket)
#define BCAP 2560  // recs per bucket region (mean 2048, sigma~45 -> +11 sigma)
#define EPW 2048   // edges per binning workgroup

using bf16x8 = __attribute__((ext_vector_type(8))) short;
using f32x4  = __attribute__((ext_vector_type(4))) float;

__device__ __forceinline__ short f2bf(float f) {
    __hip_bfloat16 h = __float2bfloat16(f);   // RNE
    return *reinterpret_cast<short*>(&h);
}
__device__ __forceinline__ float bflo(unsigned u) {  // low ushort -> f32
    return __builtin_bit_cast(float, u << 16);
}
__device__ __forceinline__ float bfhi(unsigned u) {  // high ushort -> f32
    return __builtin_bit_cast(float, u & 0xFFFF0000u);
}

// ---------------- init bucket cursors to region bases ---------------------
__global__ __launch_bounds__(512) void k_init(unsigned* __restrict__ bcur, int NBK) {
    int t = threadIdx.x;
    if (t < NBK) bcur[t] = (unsigned)t * BCAP;
}

// ---------------- bin edges into per-bucket regions -----------------------
__global__ __launch_bounds__(256) void k_bin(const int* __restrict__ src,
                                             const int* __restrict__ dst, int E,
                                             unsigned* __restrict__ bcur,
                                             unsigned* __restrict__ binned, int NBK) {
    __shared__ unsigned hist[512], lbase[512], lcur[512];
    int t = threadIdx.x;
    for (int i = t; i < NBK; i += 256) { hist[i] = 0u; lcur[i] = 0u; }
    __syncthreads();
    int base = blockIdx.x * EPW;
#pragma unroll
    for (int i = 0; i < EPW / 256; ++i) {
        int e = base + i * 256 + t;
        if (e < E) atomicAdd(&hist[((unsigned)dst[e]) >> BSH], 1u);
    }
    __syncthreads();
    for (int i = t; i < NBK; i += 256) {
        unsigned c = hist[i];
        lbase[i] = c ? atomicAdd(&bcur[i], c) : 0u;
    }
    __syncthreads();
#pragma unroll
    for (int i = 0; i < EPW / 256; ++i) {
        int e = base + i * 256 + t;
        if (e < E) {
            unsigned d = (unsigned)dst[e];
            unsigned bk = d >> BSH;
            unsigned pos = lbase[bk] + atomicAdd(&lcur[bk], 1u);
            binned[pos] = (d << 16) | (unsigned)src[e];
        }
    }
}

// ---------------- per-bucket degree -> dinv (contiguous writes) -----------
__global__ __launch_bounds__(256) void k_deg2(const unsigned* __restrict__ bcur,
                                              const unsigned* __restrict__ binned,
                                              float* __restrict__ dinv, int N) {
    int b = blockIdx.x, t = threadIdx.x;
    __shared__ unsigned hist[128];
    if (t < 128) hist[t] = 0u;
    __syncthreads();
    unsigned cnt = bcur[b] - (unsigned)b * BCAP;
    const unsigned* recs = binned + (size_t)b * BCAP;
    for (unsigned i = t; i < cnt; i += 256)
        atomicAdd(&hist[(recs[i] >> 16) & 127u], 1u);
    __syncthreads();
    if (t < 128) {
        int node = b * 128 + t;
        if (node < N) dinv[node] = rsqrtf((float)hist[t] + 1.0f);  // +1 self-loop
    }
}

// ---------------- pack W into per-lane B-fragment order -------------------
__global__ __launch_bounds__(256) void k_packw(const float* __restrict__ W,
                                               unsigned short* __restrict__ Bpack) {
    int e = blockIdx.x * 256 + threadIdx.x;   // 0..16383
    int j = e & 7;
    int lane = (e >> 3) & 63;
    int ct = (e >> 9) & 3;
    int s = e >> 11;
    int c = ct * 16 + (lane & 15);
    int k = s * 32 + (lane >> 4) * 8 + j;
    Bpack[e] = (unsigned short)f2bf(W[c * IC + k]);
}

// ---------------- MFMA linear + L2-normalize*1.8, scaled by dinv ----------
// Per-tile launch (782 blocks = ~3/CU): Bpack staged to LDS per block.
__global__ __launch_bounds__(256) void k_linnorm_mfma(
    const float* __restrict__ x, const unsigned short* __restrict__ Bpack,
    const float* __restrict__ b, const float* __restrict__ dinv,
    unsigned short* __restrict__ g, int N) {
    __shared__ uint4 bp[2048];  // 32 KB

    const uint4* bg = (const uint4*)Bpack;
#pragma unroll
    for (int i = 0; i < 8; ++i) bp[i * 256 + threadIdx.x] = bg[i * 256 + threadIdx.x];
    __syncthreads();

    int lane = threadIdx.x & 63;
    int w = threadIdx.x >> 6;
    int row0 = blockIdx.x * 64 + w * 16;
    if (row0 >= N) return;

    int r = lane & 15;        // A-row / D-col index
    int grp = lane >> 4;      // k-group / D-row group

    int rowA = row0 + r; if (rowA >= N) rowA = N - 1;
    const float* xr = x + (size_t)rowA * IC;

    f32x4 acc[4];
#pragma unroll
    for (int ct = 0; ct < 4; ++ct) {
        float bb = b[ct * 16 + r];
        acc[ct] = (f32x4){bb, bb, bb, bb};
    }

    const bf16x8* bpv = (const bf16x8*)bp;
#pragma unroll
    for (int s = 0; s < 8; ++s) {
        const float4* pa = (const float4*)(xr + s * 32 + grp * 8);
        float4 v0 = pa[0], v1 = pa[1];
        bf16x8 a;
        a[0] = f2bf(v0.x); a[1] = f2bf(v0.y); a[2] = f2bf(v0.z); a[3] = f2bf(v0.w);
        a[4] = f2bf(v1.x); a[5] = f2bf(v1.y); a[6] = f2bf(v1.z); a[7] = f2bf(v1.w);
#pragma unroll
        for (int ct = 0; ct < 4; ++ct) {
            bf16x8 bfr = bpv[(s * 4 + ct) * 64 + lane];
            acc[ct] = __builtin_amdgcn_mfma_f32_16x16x32_bf16(a, bfr, acc[ct], 0, 0, 0);
        }
    }

    // per-row: row = row0 + grp*4 + reg, col = ct*16 + r
#pragma unroll
    for (int reg = 0; reg < 4; ++reg) {
        float ss = 0.f;
#pragma unroll
        for (int ct = 0; ct < 4; ++ct) ss += acc[ct][reg] * acc[ct][reg];
#pragma unroll
        for (int o = 1; o < 16; o <<= 1) ss += __shfl_xor(ss, o, 16);

        int rowg = row0 + grp * 4 + reg;
        int rc = rowg < N ? rowg : N - 1;
        float sc = 1.8f / fmaxf(sqrtf(ss), 1e-12f) * dinv[rc];
        if (rowg < N) {
            unsigned short* go = g + (size_t)rowg * ZD + r;
#pragma unroll
            for (int ct = 0; ct < 4; ++ct)
                go[ct * 16] = (unsigned short)f2bf(acc[ct][reg] * sc);
        }
    }
}

// ---------------- per-quarter-bucket local CSR + 16-wide gather -----------
// WG = (bucket b, quarter qt): 32 dst nodes, 8 per wave. 16-lane group = one
// edge slot; lane holds 4 channels (uint2 of bf16). 16 edges in flight.
__global__ __launch_bounds__(256) void k_gather2(
    const unsigned* __restrict__ bcur, const unsigned* __restrict__ binned,
    const float* __restrict__ dinv, const unsigned short* __restrict__ g,
    float* __restrict__ out, int N) {
    int wg = blockIdx.x, b = wg >> 2, qt = wg & 3;
    __shared__ unsigned hist[64], rp[65], lcu[64];
    __shared__ unsigned short lcsr[1040];   // cap 1024 (mean 512, +22sigma) +16 pad
    int t = threadIdx.x, lane = t & 63, w = t >> 6;
    if (t < 64) hist[t] = 0u;
    __syncthreads();

    unsigned cnt = bcur[b] - (unsigned)b * BCAP;
    const unsigned* recs = binned + (size_t)b * BCAP;

    for (unsigned i = t; i < cnt; i += 256) {
        unsigned dl = (recs[i] >> 16) & 127u;
        if ((int)(dl >> 5) == qt) atomicAdd(&hist[dl & 31u], 1u);
    }
    __syncthreads();
    if (w == 0) {  // wave 0: 64-lane inclusive scan (entries 32..63 are zero)
        unsigned v = hist[lane], incl = v;
#pragma unroll
        for (int d = 1; d < 64; d <<= 1) {
            unsigned u = __shfl_up(incl, d, 64);
            if (lane >= d) incl += u;
        }
        rp[lane + 1] = incl;
        if (lane == 0) rp[0] = 0u;
        lcu[lane] = incl - v;  // exclusive base as running cursor
    }
    __syncthreads();
    for (unsigned i = t; i < cnt; i += 256) {
        unsigned rec = recs[i];
        unsigned dl = (rec >> 16) & 127u;
        if ((int)(dl >> 5) == qt) {
            unsigned p = atomicAdd(&lcu[dl & 31u], 1u);
            lcsr[p] = (unsigned short)(rec & 0xFFFFu);
        }
    }
    __syncthreads();

    int sub = lane & 15;     // channel quad: ch = sub*4 .. sub*4+3
    int grp = lane >> 4;     // edge slot within the 4-wide group
    float gsel = (grp == 0) ? 1.f : 0.f;

    // wave w gathers nodes w*8 .. w*8+7 of this quarter
    for (int q = 0; q < 8; ++q) {
        int nl = w * 8 + q;
        int node = b * 128 + qt * 32 + nl;
        if (node >= N) break;  // uniform per wave
        unsigned j = rp[nl], je = rp[nl + 1];

        // self-loop term, group 0 only (groups are summed at the end)
        uint2 sv = *(const uint2*)(g + (size_t)node * ZD + sub * 4);
        float a0 = bflo(sv.x) * gsel, a1 = bfhi(sv.x) * gsel;
        float a2 = bflo(sv.y) * gsel, a3 = bfhi(sv.y) * gsel;

        for (; j + 16 <= je; j += 16) {          // 16 edges in flight per wave
            unsigned short s0 = lcsr[j + grp];
            unsigned short s1 = lcsr[j + 4 + grp];
            unsigned short s2 = lcsr[j + 8 + grp];
            unsigned short s3 = lcsr[j + 12 + grp];
            uint2 u0 = *(const uint2*)(g + (size_t)s0 * ZD + sub * 4);
            uint2 u1 = *(const uint2*)(g + (size_t)s1 * ZD + sub * 4);
            uint2 u2 = *(const uint2*)(g + (size_t)s2 * ZD + sub * 4);
            uint2 u3 = *(const uint2*)(g + (size_t)s3 * ZD + sub * 4);
            a0 += bflo(u0.x); a1 += bfhi(u0.x); a2 += bflo(u0.y); a3 += bfhi(u0.y);
            a0 += bflo(u1.x); a1 += bfhi(u1.x); a2 += bflo(u1.y); a3 += bfhi(u1.y);
            a0 += bflo(u2.x); a1 += bfhi(u2.x); a2 += bflo(u2.y); a3 += bfhi(u2.y);
            a0 += bflo(u3.x); a1 += bfhi(u3.x); a2 += bflo(u3.y); a3 += bfhi(u3.y);
        }
        if (j < je) {                            // one predicated 16-wide block
#pragma unroll
            for (int k = 0; k < 4; ++k) {
                unsigned e = j + 4 * k + grp;
                unsigned short s = lcsr[e];      // in-bounds (padded array)
                if (e >= je) s = 0;              // clamp index: finite values only
                uint2 u = *(const uint2*)(g + (size_t)s * ZD + sub * 4);
                float m = (e < je) ? 1.f : 0.f;
                a0 = fmaf(bflo(u.x), m, a0); a1 = fmaf(bfhi(u.x), m, a1);
                a2 = fmaf(bflo(u.y), m, a2); a3 = fmaf(bfhi(u.y), m, a3);
            }
        }

        // sum the 4 edge-groups (each group holds all 64 channels)
#pragma unroll
        for (int o = 16; o < 64; o <<= 1) {
            a0 += __shfl_xor(a0, o, 64); a1 += __shfl_xor(a1, o, 64);
            a2 += __shfl_xor(a2, o, 64); a3 += __shfl_xor(a3, o, 64);
        }
        if (grp == 0) {
            float dv = dinv[node];
            float4 o4 = {a0 * dv, a1 * dv, a2 * dv, a3 * dv};
            *(float4*)(out + (size_t)node * ZD + sub * 4) = o4;
        }
    }
}

extern "C" void kernel_launch(void* const* d_in, const int* in_sizes, int n_in,
                              void* d_out, int out_size, void* d_ws, size_t ws_size,
                              hipStream_t stream) {
    const float* x = (const float*)d_in[0];
    const float* W = (const float*)d_in[1];
    const float* b = (const float*)d_in[2];
    const int* edge_index = (const int*)d_in[3];

    const int N = in_sizes[0] / IC;   // 50000
    const int E = in_sizes[3] / 2;    // 800000
    const int* src = edge_index;
    const int* dst = edge_index + E;
    float* out = (float*)d_out;

    const int NBK = (N + 127) >> BSH;   // 391 buckets

    // ---- workspace carve-up (256B aligned) ----
    char* p = (char*)d_ws;
    auto carve = [&](size_t bytes) {
        char* r = p;
        p += (bytes + 255) & ~(size_t)255;
        return r;
    };
    unsigned short* g      = (unsigned short*)carve((size_t)N * ZD * sizeof(unsigned short));
    float*          dinv   = (float*)         carve((size_t)N * sizeof(float));
    unsigned*       bcur   = (unsigned*)      carve(512 * sizeof(unsigned));
    unsigned short* Bpack  = (unsigned short*)carve(16384 * sizeof(unsigned short));
    unsigned*       binned = (unsigned*)      carve((size_t)NBK * BCAP * sizeof(unsigned));

    k_init<<<1, 512, 0, stream>>>(bcur, NBK);
    k_packw<<<64, 256, 0, stream>>>(W, Bpack);
    k_bin<<<(E + EPW - 1) / EPW, 256, 0, stream>>>(src, dst, E, bcur, binned, NBK);
    k_deg2<<<NBK, 256, 0, stream>>>(bcur, binned, dinv, N);
    k_linnorm_mfma<<<(N + 63) / 64, 256, 0, stream>>>(x, Bpack, b, dinv, g, N);
    k_gather2<<<4 * NBK, 256, 0, stream>>>(bcur, binned, dinv, g, out, N);
}